// Round 4
// baseline (538.655 us; speedup 1.0000x reference)
//
#include <hip/hip_runtime.h>
#include <math.h>

#define Bn   2048
#define Ln   200
#define En   64
#define Vn   100000
#define FEATn 1664
#define LT   32
#define LPAD 224     // 7 * 32

typedef short s4v __attribute__((ext_vector_type(4)));
typedef short s8v __attribute__((ext_vector_type(8)));
typedef float f4v __attribute__((ext_vector_type(4)));

__device__ __forceinline__ short f2bf(float f) {
  union { float f; unsigned u; } v; v.f = f;
  unsigned r = v.u + 0x7FFFu + ((v.u >> 16) & 1u);   // RNE
  return (short)(r >> 16);
}
__device__ __forceinline__ float bf2f(short s) {
  union { unsigned u; float f; } v;
  v.u = ((unsigned)(unsigned short)s) << 16;
  return v.f;
}

// fragment k-mapping shared by prep (B-side) and attn (A-side):
// k = ks*32 + lg*4 + (jj&3) + ((jj>>2)<<4)
__device__ __forceinline__ int frag_k(int ks, int lg, int jj) {
  return ks * 32 + lg * 4 + (jj & 3) + ((jj >> 2) << 4);
}

// ---------------- block-wide sum (256 threads = 4 waves) --------------------
__device__ __forceinline__ float blk_sum(float v, float* shred) {
  #pragma unroll
  for (int o = 32; o > 0; o >>= 1) v += __shfl_down(v, o, 64);
  const int t = threadIdx.x;
  __syncthreads();
  if ((t & 63) == 0) shred[t >> 6] = v;
  __syncthreads();
  return shred[0] + shred[1] + shred[2] + shred[3];
}

// ---------------- K0: prep — fragment-ordered bf16 weights ------------------
__global__ __launch_bounds__(256) void k_prep(
    const float* __restrict__ A1, const float* __restrict__ A2,
    short* __restrict__ W1f, short* __restrict__ W2f, short* __restrict__ A1s)
{
  int i = blockIdx.x * 256 + threadIdx.x;
  if (i < 32768) {
    int jj = i & 7, lane = (i >> 3) & 63, nt = (i >> 9) & 3,
        ks = (i >> 11) & 3, w = (i >> 13) & 3;
    int col = w * 64 + nt * 16 + (lane & 15);
    int lg = lane >> 4;
    float v;
    if (ks < 2) {
      int k = frag_k(ks, lg, jj);
      v = A1[(64 + k) * 256 + col] - A1[(128 + k) * 256 + col];
    } else {
      int k = frag_k(ks - 2, lg, jj);
      v = A1[(192 + k) * 256 + col];
    }
    W1f[i] = f2bf(v);
  } else if (i < 65536) {
    int u = i - 32768;
    int jj = u & 7, lane = (u >> 3) & 63, nt = (u >> 9) & 1,
        ks = (u >> 10) & 7, w = (u >> 13) & 3;
    int col = w * 32 + nt * 16 + (lane & 15);
    int lg = lane >> 4;
    int k = frag_k(ks, lg, jj);
    W2f[u] = f2bf(A2[k * 128 + col]);
  } else if (i < 81920) {
    int u = i - 65536;
    int e = u >> 8, j = u & 255;
    A1s[u] = f2bf(A1[e * 256 + j] + A1[(128 + e) * 256 + j]);
  }
}

// ---------------- K1: small gathers + numeric proj + author/tag pools -------
__global__ __launch_bounds__(256) void k_gather(
    const int* __restrict__ user_cat, const float* __restrict__ user_num,
    const int* __restrict__ ctx_cat,  const float* __restrict__ ctx_num,
    const int* __restrict__ item_cat, const float* __restrict__ item_num,
    const float* __restrict__ user_emb, const float* __restrict__ item_emb,
    const float* __restrict__ ctx_emb,
    const float* __restrict__ Wu, const float* __restrict__ bu,
    const float* __restrict__ Wi, const float* __restrict__ bi,
    const float* __restrict__ Wc, const float* __restrict__ bc,
    const int* __restrict__ hist_author, const int* __restrict__ hist_tag,
    const int* __restrict__ hist_mask,
    float* __restrict__ base)
{
  __shared__ float sRed[8][64];
  __shared__ float sNv[4];
  const int b = blockIdx.x, t = threadIdx.x;
  float* out = base + (size_t)b * FEATn;

  for (int f = t; f < 1344; f += 256) {
    float v;
    if (f < 384) {
      int n = f >> 6, e = f & 63;
      int id = user_cat[b * 6 + n];
      v = user_emb[((size_t)n * Vn + id) * 64 + e];
    } else if (f < 896) {
      int g = f - 384; int n = g >> 6, e = g & 63;
      int id = item_cat[b * 8 + n];
      v = item_emb[((size_t)n * Vn + id) * 64 + e];
    } else if (f < 1152) {
      int g = f - 896; int n = g >> 6, e = g & 63;
      int id = ctx_cat[b * 4 + n];
      v = ctx_emb[((size_t)n * Vn + id) * 64 + e];
    } else {
      int g = f - 1152; int wch = g >> 6, e = g & 63;
      float s;
      if (wch == 0) {
        s = bu[e];
        #pragma unroll
        for (int d = 0; d < 8; d++) s += user_num[b * 8 + d] * Wu[d * 64 + e];
      } else if (wch == 1) {
        s = bi[e];
        #pragma unroll
        for (int d = 0; d < 6; d++) s += item_num[b * 6 + d] * Wi[d * 64 + e];
      } else {
        s = bc[e];
        #pragma unroll
        for (int d = 0; d < 4; d++) s += ctx_num[b * 4 + d] * Wc[d * 64 + e];
      }
      v = fmaxf(s, 0.f);
    }
    out[f] = v;
  }

  const float* itemA = item_emb + (size_t)Vn * 64;
  const float* itemT = item_emb + (size_t)7 * Vn * 64;
  const int e = t & 63, wg = t >> 6;
  float aa = 0.f, tg = 0.f, nv = 0.f;
  for (int l = wg; l < Ln; l += 4) {
    if (hist_mask[b * Ln + l] > 0) {      // wave-uniform
      aa += itemA[(size_t)hist_author[b * Ln + l] * 64 + e];
      tg += itemT[(size_t)hist_tag[b * Ln + l] * 64 + e];
      nv += 1.f;
    }
  }
  sRed[wg][e] = aa; sRed[4 + wg][e] = tg;
  if (e == 0) sNv[wg] = nv;
  __syncthreads();
  if (t < 64) {
    float ap = sRed[0][t] + sRed[1][t] + sRed[2][t] + sRed[3][t];
    float tp = sRed[4][t] + sRed[5][t] + sRed[6][t] + sRed[7][t];
    float nvalid = sNv[0] + sNv[1] + sNv[2] + sNv[3];
    float inv = 1.f / fmaxf(nvalid, 1e-6f);
    out[1408 + t] = ap * inv;
    out[1472 + t] = tp * inv;
  }
}

// ---------------- K1b: qterm[b][256] = a1 + q @ A1sum ------------------------
__global__ __launch_bounds__(256) void k_qterm(
    const float* __restrict__ base, const short* __restrict__ A1s,
    const float* __restrict__ a1, float* __restrict__ qterm)
{
  __shared__ float sQ[64];
  const int b = blockIdx.x, t = threadIdx.x;
  if (t < 64) sQ[t] = base[(size_t)b * FEATn + 384 + t];
  __syncthreads();
  float s = a1[t];
  #pragma unroll 8
  for (int e = 0; e < 64; e++) s += sQ[e] * bf2f(A1s[e * 256 + t]);
  qterm[(size_t)b * 256 + t] = s;
}

// ---------------- K2: fused DIN attention (bf16 MFMA, K=64 fused W1) --------
// One b per block. W1c = (A1[64:128]-A1[128:192]) + diag(q) * A1[192:256].
__global__ __launch_bounds__(256, 3) void k_attn(
    const int* __restrict__ hist_ids, const int* __restrict__ hist_mask,
    const float* __restrict__ item_emb,
    const short* __restrict__ W1f, const short* __restrict__ W2f,
    const float* __restrict__ qterm,
    const float* __restrict__ a2, const float* __restrict__ A3,
    const float* __restrict__ a3,
    float* __restrict__ base)
{
  const int t = threadIdx.x;
  const int w = t >> 6, lane = t & 63, ln = lane & 15, lg = lane >> 4;
  const int b = blockIdx.x;

  __shared__ short sH[LPAD * 64] __attribute__((aligned(16)));   // 28 KB swz
  __shared__ short sH1[32 * 256] __attribute__((aligned(16)));   // 16 KB swz
  __shared__ float sQ[64];
  __shared__ float sScore[LPAD];
  __shared__ float sMask[LPAD];
  __shared__ int   sHid[LPAD];
  __shared__ float sPart[4][32];
  __shared__ float sRed[4][64];

  const float* item0 = item_emb;

  if (t < 64)  sQ[t] = base[(size_t)b * FEATn + 384 + t];
  if (t < LPAD) {
    sMask[t] = (t < Ln && hist_mask[b * Ln + t] > 0) ? 1.f : 0.f;
    sHid[t]  = (t < Ln) ? hist_ids[b * Ln + t] : 0;
  }
  __syncthreads();

  // ---- per-b fused layer-1 weights (K=64), in registers -------------------
  s8v bw1c[2][4];
  #pragma unroll
  for (int ks = 0; ks < 2; ks++) {
    float qk[8];
    #pragma unroll
    for (int jj = 0; jj < 8; jj++) qk[jj] = sQ[frag_k(ks, lg, jj)];
    #pragma unroll
    for (int nt = 0; nt < 4; nt++) {
      s8v fh = *(const s8v*)(W1f + (((w * 4 + ks) * 4 + nt) << 9) + lane * 8);
      s8v fq = *(const s8v*)(W1f + (((w * 4 + ks + 2) * 4 + nt) << 9) + lane * 8);
      s8v fc;
      #pragma unroll
      for (int jj = 0; jj < 8; jj++)
        fc[jj] = f2bf(bf2f(fh[jj]) + qk[jj] * bf2f(fq[jj]));
      bw1c[ks][nt] = fc;
    }
  }
  s8v bw2[8][2];
  #pragma unroll
  for (int ks = 0; ks < 8; ks++)
    #pragma unroll
    for (int nt = 0; nt < 2; nt++)
      bw2[ks][nt] = *(const s8v*)(W2f + (((w * 8 + ks) * 2 + nt) << 9) + lane * 8);

  const float a2v0 = a2[w * 32 + ln], a2v1 = a2[w * 32 + 16 + ln];
  const float a3v0 = A3[w * 32 + ln], a3v1 = A3[w * 32 + 16 + ln];
  const float a3s  = a3[0];
  float qt[4];
  #pragma unroll
  for (int i = 0; i < 4; i++)
    qt[i] = qterm[(size_t)b * 256 + w * 64 + i * 16 + ln];

  // ---- single gather of all history rows -> sH (bf16, swizzled) ----------
  for (int u = t; u < LPAD * 8; u += 256) {
    int row = u >> 3, seg = u & 7;
    s8v hv = (s8v){0,0,0,0,0,0,0,0};
    if (row < Ln) {
      const float* rp = item0 + (size_t)sHid[row] * 64 + seg * 8;
      float4 f0 = *(const float4*)rp, f1 = *(const float4*)(rp + 4);
      hv = (s8v){ f2bf(f0.x), f2bf(f0.y), f2bf(f0.z), f2bf(f0.w),
                  f2bf(f1.x), f2bf(f1.y), f2bf(f1.z), f2bf(f1.w) };
    }
    *(s8v*)(sH + ((row * 64 + seg * 8) ^ ((row & 7) << 3))) = hv;
  }
  __syncthreads();

  for (int l0 = 0; l0 < LPAD; l0 += LT) {
    // ---- layer 1 (K=64, fused weights), mt serialized to save regs --------
    #pragma unroll
    for (int mt = 0; mt < 2; mt++) {
      f4v acc1[4];
      #pragma unroll
      for (int nt = 0; nt < 4; nt++)
        acc1[nt] = (f4v){qt[nt], qt[nt], qt[nt], qt[nt]};
      #pragma unroll
      for (int ks = 0; ks < 2; ks++) {
        int row = l0 + mt * 16 + ln;
        int idx = row * 64 + ks * 32 + lg * 4;
        int swz = (row & 7) << 3;
        s4v h0 = *(const s4v*)(sH + (idx ^ swz));
        s4v h1 = *(const s4v*)(sH + ((idx + 16) ^ swz));
        s8v hf = __builtin_shufflevector(h0, h1, 0,1,2,3,4,5,6,7);
        #pragma unroll
        for (int nt = 0; nt < 4; nt++)
          acc1[nt] = __builtin_amdgcn_mfma_f32_16x16x32_bf16(hf, bw1c[ks][nt], acc1[nt], 0, 0, 0);
      }
      #pragma unroll
      for (int nt = 0; nt < 4; nt++)
        #pragma unroll
        for (int r = 0; r < 4; r++) {
          int row = mt * 16 + lg * 4 + r;
          int col = w * 64 + nt * 16 + ln;
          sH1[(row * 256 + col) ^ ((row & 7) << 3)] = f2bf(fmaxf(acc1[nt][r], 0.f));
        }
    }
    __syncthreads();

    // ---- layer 2 + layer 3 ------------------------------------------------
    #pragma unroll
    for (int mt = 0; mt < 2; mt++) {
      f4v acc2[2];
      acc2[0] = (f4v){a2v0, a2v0, a2v0, a2v0};
      acc2[1] = (f4v){a2v1, a2v1, a2v1, a2v1};
      #pragma unroll
      for (int ks = 0; ks < 8; ks++) {
        int row = mt * 16 + ln;
        int idx = row * 256 + ks * 32 + lg * 4;
        int swz = (row & 7) << 3;
        s4v h0 = *(const s4v*)(sH1 + (idx ^ swz));
        s4v h1 = *(const s4v*)(sH1 + ((idx + 16) ^ swz));
        s8v af = __builtin_shufflevector(h0, h1, 0,1,2,3,4,5,6,7);
        acc2[0] = __builtin_amdgcn_mfma_f32_16x16x32_bf16(af, bw2[ks][0], acc2[0], 0, 0, 0);
        acc2[1] = __builtin_amdgcn_mfma_f32_16x16x32_bf16(af, bw2[ks][1], acc2[1], 0, 0, 0);
      }
      #pragma unroll
      for (int r = 0; r < 4; r++) {
        float s = fmaxf(acc2[0][r], 0.f) * a3v0 + fmaxf(acc2[1][r], 0.f) * a3v1;
        s += __shfl_xor(s, 1, 64);
        s += __shfl_xor(s, 2, 64);
        s += __shfl_xor(s, 4, 64);
        s += __shfl_xor(s, 8, 64);
        if (ln == 0) sPart[w][mt * 16 + lg * 4 + r] = s;
      }
    }
    __syncthreads();
    if (t < 32) sScore[l0 + t] = a3s + sPart[0][t] + sPart[1][t] + sPart[2][t] + sPart[3][t];
  }
  __syncthreads();

  // ---- softmax by wave 0 (2 barriers total) -------------------------------
  if (w == 0) {
    float s[4], e[4];
    float mx = -3.0e38f;
    #pragma unroll
    for (int i = 0; i < 4; i++) {
      int l = lane + i * 64;
      s[i] = (l < LPAD && sMask[l] > 0.f) ? sScore[l] : -3.0e38f;
      mx = fmaxf(mx, s[i]);
    }
    #pragma unroll
    for (int o = 1; o < 64; o <<= 1) mx = fmaxf(mx, __shfl_xor(mx, o, 64));
    float sum = 0.f;
    #pragma unroll
    for (int i = 0; i < 4; i++) {
      int l = lane + i * 64;
      e[i] = (l < LPAD && sMask[l] > 0.f) ? expf(s[i] - mx) : 0.f;
      sum += e[i];
    }
    #pragma unroll
    for (int o = 1; o < 64; o <<= 1) sum += __shfl_xor(sum, o, 64);
    float invS = 1.f / fmaxf(sum, 1e-30f);
    #pragma unroll
    for (int i = 0; i < 4; i++) {
      int l = lane + i * 64;
      if (l < LPAD) sScore[l] = e[i] * invS;
    }
  }
  __syncthreads();

  // ---- hist_att from LDS (branchless: masked weights are exactly 0) -------
  {
    const int e = t & 63, wg = t >> 6;
    float aw = 0.f;
    for (int l = wg; l < Ln; l += 4)
      aw += sScore[l] * bf2f(sH[(l * 64 + e) ^ ((l & 7) << 3)]);
    sRed[wg][e] = aw;
  }
  __syncthreads();
  if (t < 64) {
    float ha = sRed[0][t] + sRed[1][t] + sRed[2][t] + sRed[3][t];
    float tv = sQ[t];
    float* out = base + (size_t)b * FEATn;
    out[1344 + t] = ha;
    out[1536 + t] = tv * ha;
    out[1600 + t] = tv - ha;
  }
}

// ---------------- K3: bf16 MFMA GEMM  C = act(A @ W + bias) ------------------
// A: MxK f32 row-major, W: KxN f32 row-major, C: MxN f32.
// Computes C^T tiles (A-operand = W^T fragments) so C-store is float4.
// Block tile 64x64, BK=32, 4 waves in 2x2 (wm, wn).
__global__ __launch_bounds__(256) void k_gemm_mfma(
    const float* __restrict__ A, const float* __restrict__ W,
    const float* __restrict__ bias, float* __restrict__ C,
    int N, int K, int relu)
{
  __shared__ short sA[64 * 32] __attribute__((aligned(16)));  // [m][k] bf16 swz
  __shared__ short sW[64 * 32] __attribute__((aligned(16)));  // [n][k] bf16 swz
  const int t = threadIdx.x;
  const int w = t >> 6, lane = t & 63, ln = lane & 15, lg = lane >> 4;
  const int m0 = blockIdx.x * 64, n0 = blockIdx.y * 64;
  const int wm = (w & 1) * 32, wn = (w >> 1) * 32;

  f4v acc[2][2] = {{(f4v){0,0,0,0},(f4v){0,0,0,0}},{(f4v){0,0,0,0},(f4v){0,0,0,0}}};

  for (int k0 = 0; k0 < K; k0 += 32) {
    #pragma unroll
    for (int i = 0; i < 2; i++) {        // A tile 64x32 -> bf16
      int idx = t + i * 256;
      int r = idx >> 3, kq = (idx & 7) << 2;
      float4 a4 = *(const float4*)(A + (size_t)(m0 + r) * K + k0 + kq);
      s4v v = { f2bf(a4.x), f2bf(a4.y), f2bf(a4.z), f2bf(a4.w) };
      *(s4v*)(sA + ((r * 32 + kq) ^ ((r & 7) << 2))) = v;
    }
    #pragma unroll
    for (int i = 0; i < 2; i++) {        // W tile 32x64 -> transposed bf16
      int idx = t + i * 256;
      int kk = idx >> 4, c4 = (idx & 15) << 2;
      float4 w4 = *(const float4*)(W + (size_t)(k0 + kk) * N + n0 + c4);
      sW[((c4 + 0) * 32 + kk) ^ (((c4 + 0) & 7) << 2)] = f2bf(w4.x);
      sW[((c4 + 1) * 32 + kk) ^ (((c4 + 1) & 7) << 2)] = f2bf(w4.y);
      sW[((c4 + 2) * 32 + kk) ^ (((c4 + 2) & 7) << 2)] = f2bf(w4.z);
      sW[((c4 + 3) * 32 + kk) ^ (((c4 + 3) & 7) << 2)] = f2bf(w4.w);
    }
    __syncthreads();

    s8v af[2], wf[2];
    #pragma unroll
    for (int mt = 0; mt < 2; mt++) {
      int row = wm + mt * 16 + ln;
      int idx = row * 32 + lg * 4, swz = (row & 7) << 2;
      s4v h0 = *(const s4v*)(sA + (idx ^ swz));
      s4v h1 = *(const s4v*)(sA + ((idx + 16) ^ swz));
      af[mt] = __builtin_shufflevector(h0, h1, 0,1,2,3,4,5,6,7);
    }
    #pragma unroll
    for (int nt = 0; nt < 2; nt++) {
      int row = wn + nt * 16 + ln;
      int idx = row * 32 + lg * 4, swz = (row & 7) << 2;
      s4v h0 = *(const s4v*)(sW + (idx ^ swz));
      s4v h1 = *(const s4v*)(sW + ((idx + 16) ^ swz));
      wf[nt] = __builtin_shufflevector(h0, h1, 0,1,2,3,4,5,6,7);
    }
    #pragma unroll
    for (int mt = 0; mt < 2; mt++)
      #pragma unroll
      for (int nt = 0; nt < 2; nt++)
        acc[mt][nt] = __builtin_amdgcn_mfma_f32_16x16x32_bf16(wf[nt], af[mt], acc[mt][nt], 0, 0, 0);
    __syncthreads();
  }

  // D[row=n][col=m]: lane(ln,lg) holds n = nt*16+4lg+r, m = mt*16+ln
  #pragma unroll
  for (int mt = 0; mt < 2; mt++)
    #pragma unroll
    for (int nt = 0; nt < 2; nt++) {
      int n = n0 + wn + nt * 16 + lg * 4;
      int m = m0 + wm + mt * 16 + ln;
      float4 bz = *(const float4*)(bias + n);
      float4 o;
      o.x = acc[mt][nt][0] + bz.x; o.y = acc[mt][nt][1] + bz.y;
      o.z = acc[mt][nt][2] + bz.z; o.w = acc[mt][nt][3] + bz.w;
      if (relu) {
        o.x = fmaxf(o.x, 0.f); o.y = fmaxf(o.y, 0.f);
        o.z = fmaxf(o.z, 0.f); o.w = fmaxf(o.w, 0.f);
      }
      *(float4*)(C + (size_t)m * N + n) = o;
    }
}

// ---------------- K4: DCN cross (3 iters) + final head ----------------------
__global__ __launch_bounds__(256) void k_cross_final(
    const float* __restrict__ base, const float* __restrict__ cross_w,
    const float* __restrict__ cross_b, const float* __restrict__ deep3,
    const float* __restrict__ Wh, const float* __restrict__ bh,
    float* __restrict__ out)
{
  __shared__ float shred[4];
  const int b = blockIdx.x, t = threadIdx.x;
  const float* br = base + (size_t)b * FEATn;
  float bs[7], xl[7];
  #pragma unroll
  for (int j = 0; j < 7; j++) {
    int i = t + j * 256;
    float v = (i < FEATn) ? br[i] : 0.f;
    bs[j] = v; xl[j] = v;
  }
  for (int k = 0; k < 3; k++) {
    float p = 0.f;
    #pragma unroll
    for (int j = 0; j < 7; j++) {
      int i = t + j * 256;
      if (i < FEATn) p += xl[j] * cross_w[k * FEATn + i];
    }
    float xw = blk_sum(p, shred);
    #pragma unroll
    for (int j = 0; j < 7; j++) {
      int i = t + j * 256;
      if (i < FEATn) xl[j] = bs[j] * xw + cross_b[k * FEATn + i] + xl[j];
    }
  }
  float p = 0.f;
  #pragma unroll
  for (int j = 0; j < 7; j++) {
    int i = t + j * 256;
    if (i < FEATn) p += xl[j] * Wh[i];
  }
  p += deep3[(size_t)b * 256 + t] * Wh[FEATn + t];
  float tot = blk_sum(p, shred);
  if (t == 0) out[b] = tot + bh[0];
}

// ---------------- launch -----------------------------------------------------
extern "C" void kernel_launch(void* const* d_in, const int* in_sizes, int n_in,
                              void* d_out, int out_size, void* d_ws, size_t ws_size,
                              hipStream_t stream) {
  (void)in_sizes; (void)n_in; (void)out_size; (void)ws_size;
  const int*   user_cat  = (const int*)d_in[0];
  const float* user_num  = (const float*)d_in[1];
  const int*   ctx_cat   = (const int*)d_in[2];
  const float* ctx_num   = (const float*)d_in[3];
  const int*   hist_ids  = (const int*)d_in[4];
  const int*   hist_auth = (const int*)d_in[5];
  const int*   hist_tag  = (const int*)d_in[6];
  const int*   hist_mask = (const int*)d_in[7];
  const int*   item_cat  = (const int*)d_in[8];
  const float* item_num  = (const float*)d_in[9];
  const float* user_emb  = (const float*)d_in[10];
  const float* item_emb  = (const float*)d_in[11];
  const float* ctx_emb   = (const float*)d_in[12];
  const float* Wu = (const float*)d_in[13];  const float* bu = (const float*)d_in[14];
  const float* Wi = (const float*)d_in[15];  const float* bi = (const float*)d_in[16];
  const float* Wc = (const float*)d_in[17];  const float* bc = (const float*)d_in[18];
  const float* A1 = (const float*)d_in[19];  const float* a1 = (const float*)d_in[20];
  const float* A2 = (const float*)d_in[21];  const float* a2 = (const float*)d_in[22];
  const float* A3 = (const float*)d_in[23];  const float* a3 = (const float*)d_in[24];
  const float* cross_w = (const float*)d_in[25];
  const float* cross_b = (const float*)d_in[26];
  const float* D1 = (const float*)d_in[27];  const float* d1 = (const float*)d_in[28];
  const float* D2 = (const float*)d_in[29];  const float* d2 = (const float*)d_in[30];
  const float* D3 = (const float*)d_in[31];  const float* d3 = (const float*)d_in[32];
  const float* Wh = (const float*)d_in[33];  const float* bh = (const float*)d_in[34];

  float* base  = (float*)d_ws;                          // B x 1664
  float* h1    = base + (size_t)Bn * FEATn;             // B x 512
  float* h2    = h1 + (size_t)Bn * 512;                 // B x 256
  float* h3    = h2 + (size_t)Bn * 256;                 // B x 256
  float* qterm = h3 + (size_t)Bn * 256;                 // B x 256
  short* W1f   = (short*)(qterm + (size_t)Bn * 256);    // 32768
  short* W2f   = W1f + 32768;                           // 32768
  short* A1s   = W2f + 32768;                           // 16384

  k_prep<<<320, 256, 0, stream>>>(A1, A2, W1f, W2f, A1s);
  k_gather<<<Bn, 256, 0, stream>>>(user_cat, user_num, ctx_cat, ctx_num,
                                   item_cat, item_num, user_emb, item_emb, ctx_emb,
                                   Wu, bu, Wi, bi, Wc, bc,
                                   hist_auth, hist_tag, hist_mask, base);
  k_qterm<<<Bn, 256, 0, stream>>>(base, A1s, a1, qterm);
  k_attn<<<Bn, 256, 0, stream>>>(hist_ids, hist_mask, item_emb,
                                 W1f, W2f, qterm, a2, A3, a3, base);
  k_gemm_mfma<<<dim3(Bn / 64, 512 / 64), 256, 0, stream>>>(base, D1, d1, h1, 512, FEATn, 1);
  k_gemm_mfma<<<dim3(Bn / 64, 256 / 64), 256, 0, stream>>>(h1, D2, d2, h2, 256, 512, 1);
  k_gemm_mfma<<<dim3(Bn / 64, 256 / 64), 256, 0, stream>>>(h2, D3, d3, h3, 256, 256, 0);
  k_cross_final<<<Bn, 256, 0, stream>>>(base, cross_w, cross_b, h3, Wh, bh,
                                        (float*)d_out);
}

// Round 5
// 310.440 us; speedup vs baseline: 1.7351x; 1.7351x over previous
//
#include <hip/hip_runtime.h>
#include <math.h>

#define Bn   2048
#define Ln   200
#define En   64
#define Vn   100000
#define FEATn 1664
#define LT   32
#define LPAD 224     // 7 * 32

typedef short s4v __attribute__((ext_vector_type(4)));
typedef short s8v __attribute__((ext_vector_type(8)));
typedef float f4v __attribute__((ext_vector_type(4)));

__device__ __forceinline__ short f2bf(float f) {
  union { float f; unsigned u; } v; v.f = f;
  unsigned r = v.u + 0x7FFFu + ((v.u >> 16) & 1u);   // RNE
  return (short)(r >> 16);
}
__device__ __forceinline__ float bf2f(short s) {
  union { unsigned u; float f; } v;
  v.u = ((unsigned)(unsigned short)s) << 16;
  return v.f;
}

// fragment k-mapping shared by prep (B-side) and attn (A-side):
// k = ks*32 + lg*4 + (jj&3) + ((jj>>2)<<4)
__device__ __forceinline__ int frag_k(int ks, int lg, int jj) {
  return ks * 32 + lg * 4 + (jj & 3) + ((jj >> 2) << 4);
}

// ---------------- block-wide sum (256 threads = 4 waves) --------------------
__device__ __forceinline__ float blk_sum(float v, float* shred) {
  #pragma unroll
  for (int o = 32; o > 0; o >>= 1) v += __shfl_down(v, o, 64);
  const int t = threadIdx.x;
  __syncthreads();
  if ((t & 63) == 0) shred[t >> 6] = v;
  __syncthreads();
  return shred[0] + shred[1] + shred[2] + shred[3];
}

// ---------------- K0: prep — fragment-ordered bf16 weights ------------------
__global__ __launch_bounds__(256) void k_prep(
    const float* __restrict__ A1, const float* __restrict__ A2,
    short* __restrict__ W1f, short* __restrict__ W2f, short* __restrict__ A1s)
{
  int i = blockIdx.x * 256 + threadIdx.x;
  if (i < 32768) {
    int jj = i & 7, lane = (i >> 3) & 63, nt = (i >> 9) & 3,
        ks = (i >> 11) & 3, w = (i >> 13) & 3;
    int col = w * 64 + nt * 16 + (lane & 15);
    int lg = lane >> 4;
    float v;
    if (ks < 2) {
      int k = frag_k(ks, lg, jj);
      v = A1[(64 + k) * 256 + col] - A1[(128 + k) * 256 + col];
    } else {
      int k = frag_k(ks - 2, lg, jj);
      v = A1[(192 + k) * 256 + col];
    }
    W1f[i] = f2bf(v);
  } else if (i < 65536) {
    int u = i - 32768;
    int jj = u & 7, lane = (u >> 3) & 63, nt = (u >> 9) & 1,
        ks = (u >> 10) & 7, w = (u >> 13) & 3;
    int col = w * 32 + nt * 16 + (lane & 15);
    int lg = lane >> 4;
    int k = frag_k(ks, lg, jj);
    W2f[u] = f2bf(A2[k * 128 + col]);
  } else if (i < 81920) {
    int u = i - 65536;
    int e = u >> 8, j = u & 255;
    A1s[u] = f2bf(A1[e * 256 + j] + A1[(128 + e) * 256 + j]);
  }
}

// ---------------- K1: small gathers + numeric proj + pools + qterm ----------
__global__ __launch_bounds__(256) void k_gather(
    const int* __restrict__ user_cat, const float* __restrict__ user_num,
    const int* __restrict__ ctx_cat,  const float* __restrict__ ctx_num,
    const int* __restrict__ item_cat, const float* __restrict__ item_num,
    const float* __restrict__ user_emb, const float* __restrict__ item_emb,
    const float* __restrict__ ctx_emb,
    const float* __restrict__ Wu, const float* __restrict__ bu,
    const float* __restrict__ Wi, const float* __restrict__ bi,
    const float* __restrict__ Wc, const float* __restrict__ bc,
    const int* __restrict__ hist_author, const int* __restrict__ hist_tag,
    const int* __restrict__ hist_mask,
    const short* __restrict__ A1s, const float* __restrict__ a1,
    float* __restrict__ base, float* __restrict__ qterm)
{
  __shared__ float sRed[8][64];
  __shared__ float sNv[4];
  __shared__ float sQ[64];
  const int b = blockIdx.x, t = threadIdx.x;
  float* out = base + (size_t)b * FEATn;

  if (t < 64) sQ[t] = item_emb[(size_t)item_cat[b * 8] * 64 + t];  // target video

  for (int f = t; f < 1344; f += 256) {
    float v;
    if (f < 384) {
      int n = f >> 6, e = f & 63;
      int id = user_cat[b * 6 + n];
      v = user_emb[((size_t)n * Vn + id) * 64 + e];
    } else if (f < 896) {
      int g = f - 384; int n = g >> 6, e = g & 63;
      int id = item_cat[b * 8 + n];
      v = item_emb[((size_t)n * Vn + id) * 64 + e];
    } else if (f < 1152) {
      int g = f - 896; int n = g >> 6, e = g & 63;
      int id = ctx_cat[b * 4 + n];
      v = ctx_emb[((size_t)n * Vn + id) * 64 + e];
    } else {
      int g = f - 1152; int wch = g >> 6, e = g & 63;
      float s;
      if (wch == 0) {
        s = bu[e];
        #pragma unroll
        for (int d = 0; d < 8; d++) s += user_num[b * 8 + d] * Wu[d * 64 + e];
      } else if (wch == 1) {
        s = bi[e];
        #pragma unroll
        for (int d = 0; d < 6; d++) s += item_num[b * 6 + d] * Wi[d * 64 + e];
      } else {
        s = bc[e];
        #pragma unroll
        for (int d = 0; d < 4; d++) s += ctx_num[b * 4 + d] * Wc[d * 64 + e];
      }
      v = fmaxf(s, 0.f);
    }
    out[f] = v;
  }

  const float* itemA = item_emb + (size_t)Vn * 64;
  const float* itemT = item_emb + (size_t)7 * Vn * 64;
  const int e = t & 63, wg = t >> 6;
  float aa = 0.f, tg = 0.f, nv = 0.f;
  for (int l = wg; l < Ln; l += 4) {
    if (hist_mask[b * Ln + l] > 0) {      // wave-uniform
      aa += itemA[(size_t)hist_author[b * Ln + l] * 64 + e];
      tg += itemT[(size_t)hist_tag[b * Ln + l] * 64 + e];
      nv += 1.f;
    }
  }
  sRed[wg][e] = aa; sRed[4 + wg][e] = tg;
  if (e == 0) sNv[wg] = nv;
  __syncthreads();
  if (t < 64) {
    float ap = sRed[0][t] + sRed[1][t] + sRed[2][t] + sRed[3][t];
    float tp = sRed[4][t] + sRed[5][t] + sRed[6][t] + sRed[7][t];
    float nvalid = sNv[0] + sNv[1] + sNv[2] + sNv[3];
    float inv = 1.f / fmaxf(nvalid, 1e-6f);
    out[1408 + t] = ap * inv;
    out[1472 + t] = tp * inv;
  }

  // qterm[b][t] = a1[t] + sum_e q[e] * A1sum[e][t]   (fused former k_qterm)
  {
    float s = a1[t];
    #pragma unroll 8
    for (int ee = 0; ee < 64; ee++) s += sQ[ee] * bf2f(A1s[ee * 256 + t]);
    qterm[(size_t)b * 256 + t] = s;
  }
}

// ---------------- K2: fused DIN attention (bf16 MFMA, K=64 fused W1) --------
// One b per block. W1c = (A1[64:128]-A1[128:192]) + diag(q) * A1[192:256].
// NOTE: no min-waves clause — round 4's (256,3) capped VGPR at 84 and spilled
// ~170 MB of scratch to HBM (WRITE_SIZE 61->171 MB, dur +31%).
__global__ __launch_bounds__(256) void k_attn(
    const int* __restrict__ hist_ids, const int* __restrict__ hist_mask,
    const float* __restrict__ item_emb,
    const short* __restrict__ W1f, const short* __restrict__ W2f,
    const float* __restrict__ qterm,
    const float* __restrict__ a2, const float* __restrict__ A3,
    const float* __restrict__ a3,
    float* __restrict__ base)
{
  const int t = threadIdx.x;
  const int w = t >> 6, lane = t & 63, ln = lane & 15, lg = lane >> 4;
  const int b = blockIdx.x;

  __shared__ short sH[LPAD * 64] __attribute__((aligned(16)));   // 28 KB swz
  __shared__ short sH1[32 * 256] __attribute__((aligned(16)));   // 16 KB swz
  __shared__ float sQ[64];
  __shared__ float sScore[LPAD];
  __shared__ float sMask[LPAD];
  __shared__ int   sHid[LPAD];
  __shared__ float sPart[4][32];
  __shared__ float sRed[4][64];

  const float* item0 = item_emb;

  if (t < 64)  sQ[t] = base[(size_t)b * FEATn + 384 + t];
  if (t < LPAD) {
    sMask[t] = (t < Ln && hist_mask[b * Ln + t] > 0) ? 1.f : 0.f;
    sHid[t]  = (t < Ln) ? hist_ids[b * Ln + t] : 0;
  }
  __syncthreads();

  // ---- per-b fused layer-1 weights (K=64), in registers -------------------
  s8v bw1c[2][4];
  #pragma unroll
  for (int ks = 0; ks < 2; ks++) {
    float qk[8];
    #pragma unroll
    for (int jj = 0; jj < 8; jj++) qk[jj] = sQ[frag_k(ks, lg, jj)];
    #pragma unroll
    for (int nt = 0; nt < 4; nt++) {
      s8v fh = *(const s8v*)(W1f + (((w * 4 + ks) * 4 + nt) << 9) + lane * 8);
      s8v fq = *(const s8v*)(W1f + (((w * 4 + ks + 2) * 4 + nt) << 9) + lane * 8);
      s8v fc;
      #pragma unroll
      for (int jj = 0; jj < 8; jj++)
        fc[jj] = f2bf(bf2f(fh[jj]) + qk[jj] * bf2f(fq[jj]));
      bw1c[ks][nt] = fc;
    }
  }
  s8v bw2[8][2];
  #pragma unroll
  for (int ks = 0; ks < 8; ks++)
    #pragma unroll
    for (int nt = 0; nt < 2; nt++)
      bw2[ks][nt] = *(const s8v*)(W2f + (((w * 8 + ks) * 2 + nt) << 9) + lane * 8);

  const float a2v0 = a2[w * 32 + ln], a2v1 = a2[w * 32 + 16 + ln];
  const float a3v0 = A3[w * 32 + ln], a3v1 = A3[w * 32 + 16 + ln];
  const float a3s  = a3[0];
  float qt[4];
  #pragma unroll
  for (int i = 0; i < 4; i++)
    qt[i] = qterm[(size_t)b * 256 + w * 64 + i * 16 + ln];

  // ---- single gather of all history rows -> sH (bf16, swizzled) ----------
  for (int u = t; u < LPAD * 8; u += 256) {
    int row = u >> 3, seg = u & 7;
    s8v hv = (s8v){0,0,0,0,0,0,0,0};
    if (row < Ln) {
      const float* rp = item0 + (size_t)sHid[row] * 64 + seg * 8;
      float4 f0 = *(const float4*)rp, f1 = *(const float4*)(rp + 4);
      hv = (s8v){ f2bf(f0.x), f2bf(f0.y), f2bf(f0.z), f2bf(f0.w),
                  f2bf(f1.x), f2bf(f1.y), f2bf(f1.z), f2bf(f1.w) };
    }
    *(s8v*)(sH + ((row * 64 + seg * 8) ^ ((row & 7) << 3))) = hv;
  }
  __syncthreads();

  for (int l0 = 0; l0 < LPAD; l0 += LT) {
    // ---- layer 1 (K=64, fused weights), mt serialized to save regs --------
    #pragma unroll
    for (int mt = 0; mt < 2; mt++) {
      f4v acc1[4];
      #pragma unroll
      for (int nt = 0; nt < 4; nt++)
        acc1[nt] = (f4v){qt[nt], qt[nt], qt[nt], qt[nt]};
      #pragma unroll
      for (int ks = 0; ks < 2; ks++) {
        int row = l0 + mt * 16 + ln;
        int idx = row * 64 + ks * 32 + lg * 4;
        int swz = (row & 7) << 3;
        s4v h0 = *(const s4v*)(sH + (idx ^ swz));
        s4v h1 = *(const s4v*)(sH + ((idx + 16) ^ swz));
        s8v hf = __builtin_shufflevector(h0, h1, 0,1,2,3,4,5,6,7);
        #pragma unroll
        for (int nt = 0; nt < 4; nt++)
          acc1[nt] = __builtin_amdgcn_mfma_f32_16x16x32_bf16(hf, bw1c[ks][nt], acc1[nt], 0, 0, 0);
      }
      #pragma unroll
      for (int nt = 0; nt < 4; nt++)
        #pragma unroll
        for (int r = 0; r < 4; r++) {
          int row = mt * 16 + lg * 4 + r;
          int col = w * 64 + nt * 16 + ln;
          sH1[(row * 256 + col) ^ ((row & 7) << 3)] = f2bf(fmaxf(acc1[nt][r], 0.f));
        }
    }
    __syncthreads();

    // ---- layer 2 + layer 3 ------------------------------------------------
    #pragma unroll
    for (int mt = 0; mt < 2; mt++) {
      f4v acc2[2];
      acc2[0] = (f4v){a2v0, a2v0, a2v0, a2v0};
      acc2[1] = (f4v){a2v1, a2v1, a2v1, a2v1};
      #pragma unroll
      for (int ks = 0; ks < 8; ks++) {
        int row = mt * 16 + ln;
        int idx = row * 256 + ks * 32 + lg * 4;
        int swz = (row & 7) << 3;
        s4v h0 = *(const s4v*)(sH1 + (idx ^ swz));
        s4v h1 = *(const s4v*)(sH1 + ((idx + 16) ^ swz));
        s8v af = __builtin_shufflevector(h0, h1, 0,1,2,3,4,5,6,7);
        acc2[0] = __builtin_amdgcn_mfma_f32_16x16x32_bf16(af, bw2[ks][0], acc2[0], 0, 0, 0);
        acc2[1] = __builtin_amdgcn_mfma_f32_16x16x32_bf16(af, bw2[ks][1], acc2[1], 0, 0, 0);
      }
      #pragma unroll
      for (int r = 0; r < 4; r++) {
        float s = fmaxf(acc2[0][r], 0.f) * a3v0 + fmaxf(acc2[1][r], 0.f) * a3v1;
        s += __shfl_xor(s, 1, 64);
        s += __shfl_xor(s, 2, 64);
        s += __shfl_xor(s, 4, 64);
        s += __shfl_xor(s, 8, 64);
        if (ln == 0) sPart[w][mt * 16 + lg * 4 + r] = s;
      }
    }
    __syncthreads();
    if (t < 32) sScore[l0 + t] = a3s + sPart[0][t] + sPart[1][t] + sPart[2][t] + sPart[3][t];
  }
  __syncthreads();

  // ---- softmax by wave 0 (2 barriers total) -------------------------------
  if (w == 0) {
    float s[4], e[4];
    float mx = -3.0e38f;
    #pragma unroll
    for (int i = 0; i < 4; i++) {
      int l = lane + i * 64;
      s[i] = (l < LPAD && sMask[l] > 0.f) ? sScore[l] : -3.0e38f;
      mx = fmaxf(mx, s[i]);
    }
    #pragma unroll
    for (int o = 1; o < 64; o <<= 1) mx = fmaxf(mx, __shfl_xor(mx, o, 64));
    float sum = 0.f;
    #pragma unroll
    for (int i = 0; i < 4; i++) {
      int l = lane + i * 64;
      e[i] = (l < LPAD && sMask[l] > 0.f) ? expf(s[i] - mx) : 0.f;
      sum += e[i];
    }
    #pragma unroll
    for (int o = 1; o < 64; o <<= 1) sum += __shfl_xor(sum, o, 64);
    float invS = 1.f / fmaxf(sum, 1e-30f);
    #pragma unroll
    for (int i = 0; i < 4; i++) {
      int l = lane + i * 64;
      if (l < LPAD) sScore[l] = e[i] * invS;
    }
  }
  __syncthreads();

  // ---- hist_att from LDS (branchless: masked weights are exactly 0) -------
  {
    const int e = t & 63, wg = t >> 6;
    float aw = 0.f;
    for (int l = wg; l < Ln; l += 4)
      aw += sScore[l] * bf2f(sH[(l * 64 + e) ^ ((l & 7) << 3)]);
    sRed[wg][e] = aw;
  }
  __syncthreads();
  if (t < 64) {
    float ha = sRed[0][t] + sRed[1][t] + sRed[2][t] + sRed[3][t];
    float tv = sQ[t];
    float* out = base + (size_t)b * FEATn;
    out[1344 + t] = ha;
    out[1536 + t] = tv * ha;
    out[1600 + t] = tv - ha;
  }
}

// ---------------- K3: bf16 MFMA GEMM  C = act(A @ W + bias) ------------------
// A: MxK f32 row-major, W: KxN f32 row-major, C: MxN f32.
// Computes C^T tiles (A-operand = W^T fragments) so C-store is float4.
__global__ __launch_bounds__(256) void k_gemm_mfma(
    const float* __restrict__ A, const float* __restrict__ W,
    const float* __restrict__ bias, float* __restrict__ C,
    int N, int K, int relu)
{
  __shared__ short sA[64 * 32] __attribute__((aligned(16)));  // [m][k] bf16 swz
  __shared__ short sW[64 * 32] __attribute__((aligned(16)));  // [n][k] bf16 swz
  const int t = threadIdx.x;
  const int w = t >> 6, lane = t & 63, ln = lane & 15, lg = lane >> 4;
  const int m0 = blockIdx.x * 64, n0 = blockIdx.y * 64;
  const int wm = (w & 1) * 32, wn = (w >> 1) * 32;

  f4v acc[2][2] = {{(f4v){0,0,0,0},(f4v){0,0,0,0}},{(f4v){0,0,0,0},(f4v){0,0,0,0}}};

  for (int k0 = 0; k0 < K; k0 += 32) {
    #pragma unroll
    for (int i = 0; i < 2; i++) {        // A tile 64x32 -> bf16
      int idx = t + i * 256;
      int r = idx >> 3, kq = (idx & 7) << 2;
      float4 a4 = *(const float4*)(A + (size_t)(m0 + r) * K + k0 + kq);
      s4v v = { f2bf(a4.x), f2bf(a4.y), f2bf(a4.z), f2bf(a4.w) };
      *(s4v*)(sA + ((r * 32 + kq) ^ ((r & 7) << 2))) = v;
    }
    #pragma unroll
    for (int i = 0; i < 2; i++) {        // W tile 32x64 -> transposed bf16
      int idx = t + i * 256;
      int kk = idx >> 4, c4 = (idx & 15) << 2;
      float4 w4 = *(const float4*)(W + (size_t)(k0 + kk) * N + n0 + c4);
      sW[((c4 + 0) * 32 + kk) ^ (((c4 + 0) & 7) << 2)] = f2bf(w4.x);
      sW[((c4 + 1) * 32 + kk) ^ (((c4 + 1) & 7) << 2)] = f2bf(w4.y);
      sW[((c4 + 2) * 32 + kk) ^ (((c4 + 2) & 7) << 2)] = f2bf(w4.z);
      sW[((c4 + 3) * 32 + kk) ^ (((c4 + 3) & 7) << 2)] = f2bf(w4.w);
    }
    __syncthreads();

    s8v af[2], wf[2];
    #pragma unroll
    for (int mt = 0; mt < 2; mt++) {
      int row = wm + mt * 16 + ln;
      int idx = row * 32 + lg * 4, swz = (row & 7) << 2;
      s4v h0 = *(const s4v*)(sA + (idx ^ swz));
      s4v h1 = *(const s4v*)(sA + ((idx + 16) ^ swz));
      af[mt] = __builtin_shufflevector(h0, h1, 0,1,2,3,4,5,6,7);
    }
    #pragma unroll
    for (int nt = 0; nt < 2; nt++) {
      int row = wn + nt * 16 + ln;
      int idx = row * 32 + lg * 4, swz = (row & 7) << 2;
      s4v h0 = *(const s4v*)(sW + (idx ^ swz));
      s4v h1 = *(const s4v*)(sW + ((idx + 16) ^ swz));
      wf[nt] = __builtin_shufflevector(h0, h1, 0,1,2,3,4,5,6,7);
    }
    #pragma unroll
    for (int mt = 0; mt < 2; mt++)
      #pragma unroll
      for (int nt = 0; nt < 2; nt++)
        acc[mt][nt] = __builtin_amdgcn_mfma_f32_16x16x32_bf16(wf[nt], af[mt], acc[mt][nt], 0, 0, 0);
    __syncthreads();
  }

  // D[row=n][col=m]: lane(ln,lg) holds n = nt*16+4lg+r, m = mt*16+ln
  #pragma unroll
  for (int mt = 0; mt < 2; mt++)
    #pragma unroll
    for (int nt = 0; nt < 2; nt++) {
      int n = n0 + wn + nt * 16 + lg * 4;
      int m = m0 + wm + mt * 16 + ln;
      float4 bz = *(const float4*)(bias + n);
      float4 o;
      o.x = acc[mt][nt][0] + bz.x; o.y = acc[mt][nt][1] + bz.y;
      o.z = acc[mt][nt][2] + bz.z; o.w = acc[mt][nt][3] + bz.w;
      if (relu) {
        o.x = fmaxf(o.x, 0.f); o.y = fmaxf(o.y, 0.f);
        o.z = fmaxf(o.z, 0.f); o.w = fmaxf(o.w, 0.f);
      }
      *(float4*)(C + (size_t)m * N + n) = o;
    }
}

// ---------------- K4: DCN cross (3 iters) + final head ----------------------
__global__ __launch_bounds__(256) void k_cross_final(
    const float* __restrict__ base, const float* __restrict__ cross_w,
    const float* __restrict__ cross_b, const float* __restrict__ deep3,
    const float* __restrict__ Wh, const float* __restrict__ bh,
    float* __restrict__ out)
{
  __shared__ float shred[4];
  const int b = blockIdx.x, t = threadIdx.x;
  const float* br = base + (size_t)b * FEATn;
  float bs[7], xl[7];
  #pragma unroll
  for (int j = 0; j < 7; j++) {
    int i = t + j * 256;
    float v = (i < FEATn) ? br[i] : 0.f;
    bs[j] = v; xl[j] = v;
  }
  for (int k = 0; k < 3; k++) {
    float p = 0.f;
    #pragma unroll
    for (int j = 0; j < 7; j++) {
      int i = t + j * 256;
      if (i < FEATn) p += xl[j] * cross_w[k * FEATn + i];
    }
    float xw = blk_sum(p, shred);
    #pragma unroll
    for (int j = 0; j < 7; j++) {
      int i = t + j * 256;
      if (i < FEATn) xl[j] = bs[j] * xw + cross_b[k * FEATn + i] + xl[j];
    }
  }
  float p = 0.f;
  #pragma unroll
  for (int j = 0; j < 7; j++) {
    int i = t + j * 256;
    if (i < FEATn) p += xl[j] * Wh[i];
  }
  p += deep3[(size_t)b * 256 + t] * Wh[FEATn + t];
  float tot = blk_sum(p, shred);
  if (t == 0) out[b] = tot + bh[0];
}

// ---------------- launch -----------------------------------------------------
extern "C" void kernel_launch(void* const* d_in, const int* in_sizes, int n_in,
                              void* d_out, int out_size, void* d_ws, size_t ws_size,
                              hipStream_t stream) {
  (void)in_sizes; (void)n_in; (void)out_size; (void)ws_size;
  const int*   user_cat  = (const int*)d_in[0];
  const float* user_num  = (const float*)d_in[1];
  const int*   ctx_cat   = (const int*)d_in[2];
  const float* ctx_num   = (const float*)d_in[3];
  const int*   hist_ids  = (const int*)d_in[4];
  const int*   hist_auth = (const int*)d_in[5];
  const int*   hist_tag  = (const int*)d_in[6];
  const int*   hist_mask = (const int*)d_in[7];
  const int*   item_cat  = (const int*)d_in[8];
  const float* item_num  = (const float*)d_in[9];
  const float* user_emb  = (const float*)d_in[10];
  const float* item_emb  = (const float*)d_in[11];
  const float* ctx_emb   = (const float*)d_in[12];
  const float* Wu = (const float*)d_in[13];  const float* bu = (const float*)d_in[14];
  const float* Wi = (const float*)d_in[15];  const float* bi = (const float*)d_in[16];
  const float* Wc = (const float*)d_in[17];  const float* bc = (const float*)d_in[18];
  const float* A1 = (const float*)d_in[19];  const float* a1 = (const float*)d_in[20];
  const float* A2 = (const float*)d_in[21];  const float* a2 = (const float*)d_in[22];
  const float* A3 = (const float*)d_in[23];  const float* a3 = (const float*)d_in[24];
  const float* cross_w = (const float*)d_in[25];
  const float* cross_b = (const float*)d_in[26];
  const float* D1 = (const float*)d_in[27];  const float* d1 = (const float*)d_in[28];
  const float* D2 = (const float*)d_in[29];  const float* d2 = (const float*)d_in[30];
  const float* D3 = (const float*)d_in[31];  const float* d3 = (const float*)d_in[32];
  const float* Wh = (const float*)d_in[33];  const float* bh = (const float*)d_in[34];

  float* base  = (float*)d_ws;                          // B x 1664
  float* h1    = base + (size_t)Bn * FEATn;             // B x 512
  float* h2    = h1 + (size_t)Bn * 512;                 // B x 256
  float* h3    = h2 + (size_t)Bn * 256;                 // B x 256
  float* qterm = h3 + (size_t)Bn * 256;                 // B x 256
  short* W1f   = (short*)(qterm + (size_t)Bn * 256);    // 32768
  short* W2f   = W1f + 32768;                           // 32768
  short* A1s   = W2f + 32768;                           // 16384

  k_prep<<<320, 256, 0, stream>>>(A1, A2, W1f, W2f, A1s);
  k_gather<<<Bn, 256, 0, stream>>>(user_cat, user_num, ctx_cat, ctx_num,
                                   item_cat, item_num, user_emb, item_emb, ctx_emb,
                                   Wu, bu, Wi, bi, Wc, bc,
                                   hist_auth, hist_tag, hist_mask,
                                   A1s, a1, base, qterm);
  k_attn<<<Bn, 256, 0, stream>>>(hist_ids, hist_mask, item_emb,
                                 W1f, W2f, qterm, a2, A3, a3, base);
  k_gemm_mfma<<<dim3(Bn / 64, 512 / 64), 256, 0, stream>>>(base, D1, d1, h1, 512, FEATn, 1);
  k_gemm_mfma<<<dim3(Bn / 64, 256 / 64), 256, 0, stream>>>(h1, D2, d2, h2, 256, 512, 1);
  k_gemm_mfma<<<dim3(Bn / 64, 256 / 64), 256, 0, stream>>>(h2, D3, d3, h3, 256, 256, 0);
  k_cross_final<<<Bn, 256, 0, stream>>>(base, cross_w, cross_b, h3, Wh, bh,
                                        (float*)d_out);
}

// Round 6
// 274.898 us; speedup vs baseline: 1.9595x; 1.1293x over previous
//
#include <hip/hip_runtime.h>
#include <math.h>

#define Bn   2048
#define Ln   200
#define En   64
#define Vn   100000
#define FEATn 1664
#define LPAD 224     // 7 * 32

typedef short s4v __attribute__((ext_vector_type(4)));
typedef short s8v __attribute__((ext_vector_type(8)));
typedef float f4v __attribute__((ext_vector_type(4)));

__device__ __forceinline__ short f2bf(float f) {
  union { float f; unsigned u; } v; v.f = f;
  unsigned r = v.u + 0x7FFFu + ((v.u >> 16) & 1u);   // RNE
  return (short)(r >> 16);
}
__device__ __forceinline__ float bf2f(short s) {
  union { unsigned u; float f; } v;
  v.u = ((unsigned)(unsigned short)s) << 16;
  return v.f;
}

// fragment k-mapping shared by prep (B-side) and attn (A-side):
// k = ks*32 + lg*4 + (jj&3) + ((jj>>2)<<4)
__device__ __forceinline__ int frag_k(int ks, int lg, int jj) {
  return ks * 32 + lg * 4 + (jj & 3) + ((jj >> 2) << 4);
}

// ---------------- block-wide sum (256 threads = 4 waves) --------------------
__device__ __forceinline__ float blk_sum(float v, float* shred) {
  #pragma unroll
  for (int o = 32; o > 0; o >>= 1) v += __shfl_down(v, o, 64);
  const int t = threadIdx.x;
  __syncthreads();
  if ((t & 63) == 0) shred[t >> 6] = v;
  __syncthreads();
  return shred[0] + shred[1] + shred[2] + shred[3];
}

// ---------------- K0a: prep — fragment-ordered bf16 weights -----------------
__global__ __launch_bounds__(256) void k_prep(
    const float* __restrict__ A1, const float* __restrict__ A2,
    short* __restrict__ W1f, short* __restrict__ W2f, short* __restrict__ A1s)
{
  int i = blockIdx.x * 256 + threadIdx.x;
  if (i < 32768) {
    int jj = i & 7, lane = (i >> 3) & 63, nt = (i >> 9) & 3,
        ks = (i >> 11) & 3, w = (i >> 13) & 3;
    int col = w * 64 + nt * 16 + (lane & 15);
    int lg = lane >> 4;
    float v;
    if (ks < 2) {
      int k = frag_k(ks, lg, jj);
      v = A1[(64 + k) * 256 + col] - A1[(128 + k) * 256 + col];
    } else {
      int k = frag_k(ks - 2, lg, jj);
      v = A1[(192 + k) * 256 + col];
    }
    W1f[i] = f2bf(v);
  } else if (i < 65536) {
    int u = i - 32768;
    int jj = u & 7, lane = (u >> 3) & 63, nt = (u >> 9) & 1,
        ks = (u >> 10) & 7, w = (u >> 13) & 3;
    int col = w * 32 + nt * 16 + (lane & 15);
    int lg = lane >> 4;
    int k = frag_k(ks, lg, jj);
    W2f[u] = f2bf(A2[k * 128 + col]);
  } else if (i < 81920) {
    int u = i - 65536;
    int e = u >> 8, j = u & 255;
    A1s[u] = f2bf(A1[e * 256 + j] + A1[(128 + e) * 256 + j]);
  }
}

// ---------------- K0b: item_emb table 0 -> bf16 (L3-resident copy) ----------
__global__ __launch_bounds__(256) void k_cvt(
    const float* __restrict__ src, short* __restrict__ dst, int n4)
{
  int i = blockIdx.x * 256 + threadIdx.x;
  if (i < n4) {
    float4 f = ((const float4*)src)[i];
    s4v v = { f2bf(f.x), f2bf(f.y), f2bf(f.z), f2bf(f.w) };
    ((s4v*)dst)[i] = v;
  }
}

// ---------------- K0c: D1/D2/D3 [K][N] f32 -> [N][K] bf16 -------------------
__global__ __launch_bounds__(256) void k_trcvt(
    const float* __restrict__ D1, const float* __restrict__ D2,
    const float* __restrict__ D3,
    short* __restrict__ T1, short* __restrict__ T2, short* __restrict__ T3)
{
  __shared__ float tile[32][33];
  int blk = blockIdx.x;
  const float* src; short* dst; int K, N, b0;
  if (blk < 832)      { src = D1; dst = T1; K = 1664; N = 512; b0 = blk; }
  else if (blk < 960) { src = D2; dst = T2; K = 512;  N = 256; b0 = blk - 832; }
  else                { src = D3; dst = T3; K = 256;  N = 256; b0 = blk - 960; }
  int nbk = K / 32;
  int kb = (b0 % nbk) * 32, nb = (b0 / nbk) * 32;
  int tx = threadIdx.x & 31, ty = threadIdx.x >> 5;   // ty 0..7
  #pragma unroll
  for (int i = 0; i < 4; i++)
    tile[ty + i * 8][tx] = src[(size_t)(kb + ty + i * 8) * N + nb + tx];
  __syncthreads();
  #pragma unroll
  for (int i = 0; i < 4; i++)
    dst[(size_t)(nb + ty + i * 8) * K + kb + tx] = f2bf(tile[tx][ty + i * 8]);
}

// ---------------- K1: small gathers + numeric proj + pools + qterm ----------
__global__ __launch_bounds__(256) void k_gather(
    const int* __restrict__ user_cat, const float* __restrict__ user_num,
    const int* __restrict__ ctx_cat,  const float* __restrict__ ctx_num,
    const int* __restrict__ item_cat, const float* __restrict__ item_num,
    const float* __restrict__ user_emb, const float* __restrict__ item_emb,
    const float* __restrict__ ctx_emb,
    const float* __restrict__ Wu, const float* __restrict__ bu,
    const float* __restrict__ Wi, const float* __restrict__ bi,
    const float* __restrict__ Wc, const float* __restrict__ bc,
    const int* __restrict__ hist_author, const int* __restrict__ hist_tag,
    const int* __restrict__ hist_mask,
    const short* __restrict__ A1s, const float* __restrict__ a1,
    float* __restrict__ base, short* __restrict__ baseb,
    float* __restrict__ qterm)
{
  __shared__ float sRed[8][64];
  __shared__ float sNv[4];
  __shared__ float sQ[64];
  const int b = blockIdx.x, t = threadIdx.x;
  float* out = base + (size_t)b * FEATn;
  short* outb = baseb + (size_t)b * FEATn;

  if (t < 64) sQ[t] = item_emb[(size_t)item_cat[b * 8] * 64 + t];

  for (int f = t; f < 1344; f += 256) {
    float v;
    if (f < 384) {
      int n = f >> 6, e = f & 63;
      int id = user_cat[b * 6 + n];
      v = user_emb[((size_t)n * Vn + id) * 64 + e];
    } else if (f < 896) {
      int g = f - 384; int n = g >> 6, e = g & 63;
      int id = item_cat[b * 8 + n];
      v = item_emb[((size_t)n * Vn + id) * 64 + e];
    } else if (f < 1152) {
      int g = f - 896; int n = g >> 6, e = g & 63;
      int id = ctx_cat[b * 4 + n];
      v = ctx_emb[((size_t)n * Vn + id) * 64 + e];
    } else {
      int g = f - 1152; int wch = g >> 6, e = g & 63;
      float s;
      if (wch == 0) {
        s = bu[e];
        #pragma unroll
        for (int d = 0; d < 8; d++) s += user_num[b * 8 + d] * Wu[d * 64 + e];
      } else if (wch == 1) {
        s = bi[e];
        #pragma unroll
        for (int d = 0; d < 6; d++) s += item_num[b * 6 + d] * Wi[d * 64 + e];
      } else {
        s = bc[e];
        #pragma unroll
        for (int d = 0; d < 4; d++) s += ctx_num[b * 4 + d] * Wc[d * 64 + e];
      }
      v = fmaxf(s, 0.f);
    }
    out[f] = v;
    outb[f] = f2bf(v);
  }

  const float* itemA = item_emb + (size_t)Vn * 64;
  const float* itemT = item_emb + (size_t)7 * Vn * 64;
  const int e = t & 63, wg = t >> 6;
  float aa = 0.f, tg = 0.f, nv = 0.f;
  for (int l = wg; l < Ln; l += 4) {
    if (hist_mask[b * Ln + l] > 0) {      // wave-uniform
      aa += itemA[(size_t)hist_author[b * Ln + l] * 64 + e];
      tg += itemT[(size_t)hist_tag[b * Ln + l] * 64 + e];
      nv += 1.f;
    }
  }
  sRed[wg][e] = aa; sRed[4 + wg][e] = tg;
  if (e == 0) sNv[wg] = nv;
  __syncthreads();
  if (t < 64) {
    float ap = sRed[0][t] + sRed[1][t] + sRed[2][t] + sRed[3][t];
    float tp = sRed[4][t] + sRed[5][t] + sRed[6][t] + sRed[7][t];
    float nvalid = sNv[0] + sNv[1] + sNv[2] + sNv[3];
    float inv = 1.f / fmaxf(nvalid, 1e-6f);
    float apv = ap * inv, tpv = tp * inv;
    out[1408 + t] = apv;  outb[1408 + t] = f2bf(apv);
    out[1472 + t] = tpv;  outb[1472 + t] = f2bf(tpv);
  }

  { // qterm[b][t] = a1[t] + sum_e q[e] * A1sum[e][t]
    float s = a1[t];
    #pragma unroll 8
    for (int ee = 0; ee < 64; ee++) s += sQ[ee] * bf2f(A1s[ee * 256 + t]);
    qterm[(size_t)b * 256 + t] = s;
  }
}

// ---------------- K2: fused DIN attention (bf16 MFMA, no staging) -----------
// One b per block. h fragments load DIRECTLY from bf16 table copy (L2/L3 hot).
// LDS ~20.5 KB (was 49.6) -> occupancy VGPR-limited, ~2x round-5.
__global__ __launch_bounds__(256) void k_attn(
    const int* __restrict__ hist_ids, const int* __restrict__ hist_mask,
    const short* __restrict__ emb0b,
    const short* __restrict__ W1f, const short* __restrict__ W2f,
    const float* __restrict__ qterm,
    const float* __restrict__ a2, const float* __restrict__ A3,
    const float* __restrict__ a3,
    float* __restrict__ base, short* __restrict__ baseb)
{
  const int t = threadIdx.x;
  const int w = t >> 6, lane = t & 63, ln = lane & 15, lg = lane >> 4;
  const int b = blockIdx.x;

  __shared__ short sH1[32 * 256] __attribute__((aligned(16)));   // 16 KB swz
  __shared__ float sQ[64];
  __shared__ float sScore[LPAD];
  __shared__ float sMask[LPAD];
  __shared__ int   sHid[LPAD];
  __shared__ float sPart[4][32];
  __shared__ float sRed[4][64];

  if (t < 64)  sQ[t] = base[(size_t)b * FEATn + 384 + t];
  if (t < LPAD) {
    sMask[t] = (t < Ln && hist_mask[b * Ln + t] > 0) ? 1.f : 0.f;
    sHid[t]  = (t < Ln) ? hist_ids[b * Ln + t] : 0;
  }
  __syncthreads();

  // per-b fused layer-1 weights (K=64): W1c = W1h + diag(q)*W1q
  s8v bw1c[2][4];
  #pragma unroll
  for (int ks = 0; ks < 2; ks++) {
    float qk[8];
    #pragma unroll
    for (int jj = 0; jj < 8; jj++) qk[jj] = sQ[frag_k(ks, lg, jj)];
    #pragma unroll
    for (int nt = 0; nt < 4; nt++) {
      s8v fh = *(const s8v*)(W1f + (((w * 4 + ks) * 4 + nt) << 9) + lane * 8);
      s8v fq = *(const s8v*)(W1f + (((w * 4 + ks + 2) * 4 + nt) << 9) + lane * 8);
      s8v fc;
      #pragma unroll
      for (int jj = 0; jj < 8; jj++)
        fc[jj] = f2bf(bf2f(fh[jj]) + qk[jj] * bf2f(fq[jj]));
      bw1c[ks][nt] = fc;
    }
  }
  s8v bw2[8][2];
  #pragma unroll
  for (int ks = 0; ks < 8; ks++)
    #pragma unroll
    for (int nt = 0; nt < 2; nt++)
      bw2[ks][nt] = *(const s8v*)(W2f + (((w * 8 + ks) * 2 + nt) << 9) + lane * 8);

  const float a2v0 = a2[w * 32 + ln], a2v1 = a2[w * 32 + 16 + ln];
  const float a3v0 = A3[w * 32 + ln], a3v1 = A3[w * 32 + 16 + ln];
  const float a3s  = a3[0];
  float qt[4];
  #pragma unroll
  for (int i = 0; i < 4; i++)
    qt[i] = qterm[(size_t)b * 256 + w * 64 + i * 16 + ln];

  // hoist this lane's 14 row-ids (rows i*16 + ln)
  int idr[14];
  #pragma unroll
  for (int i = 0; i < 14; i++) idr[i] = sHid[i * 16 + ln];

  for (int l0i = 0; l0i < 7; l0i++) {
    // ---- layer 1: A-fragments straight from global bf16 table -------------
    #pragma unroll
    for (int mt = 0; mt < 2; mt++) {
      f4v acc1[4];
      #pragma unroll
      for (int nt = 0; nt < 4; nt++)
        acc1[nt] = (f4v){qt[nt], qt[nt], qt[nt], qt[nt]};
      const short* hp = emb0b + (size_t)idr[l0i * 2 + mt] * 64 + lg * 4;
      #pragma unroll
      for (int ks = 0; ks < 2; ks++) {
        s4v h0 = *(const s4v*)(hp + ks * 32);
        s4v h1 = *(const s4v*)(hp + ks * 32 + 16);
        s8v hf = __builtin_shufflevector(h0, h1, 0,1,2,3,4,5,6,7);
        #pragma unroll
        for (int nt = 0; nt < 4; nt++)
          acc1[nt] = __builtin_amdgcn_mfma_f32_16x16x32_bf16(hf, bw1c[ks][nt], acc1[nt], 0, 0, 0);
      }
      #pragma unroll
      for (int nt = 0; nt < 4; nt++)
        #pragma unroll
        for (int r = 0; r < 4; r++) {
          int row = mt * 16 + lg * 4 + r;
          int col = w * 64 + nt * 16 + ln;
          sH1[(row * 256 + col) ^ ((row & 7) << 3)] = f2bf(fmaxf(acc1[nt][r], 0.f));
        }
    }
    __syncthreads();

    // ---- layer 2 + layer 3 -------------------------------------------------
    #pragma unroll
    for (int mt = 0; mt < 2; mt++) {
      f4v acc2[2];
      acc2[0] = (f4v){a2v0, a2v0, a2v0, a2v0};
      acc2[1] = (f4v){a2v1, a2v1, a2v1, a2v1};
      #pragma unroll
      for (int ks = 0; ks < 8; ks++) {
        int row = mt * 16 + ln;
        int idx = row * 256 + ks * 32 + lg * 4;
        int swz = (row & 7) << 3;
        s4v h0 = *(const s4v*)(sH1 + (idx ^ swz));
        s4v h1 = *(const s4v*)(sH1 + ((idx + 16) ^ swz));
        s8v af = __builtin_shufflevector(h0, h1, 0,1,2,3,4,5,6,7);
        acc2[0] = __builtin_amdgcn_mfma_f32_16x16x32_bf16(af, bw2[ks][0], acc2[0], 0, 0, 0);
        acc2[1] = __builtin_amdgcn_mfma_f32_16x16x32_bf16(af, bw2[ks][1], acc2[1], 0, 0, 0);
      }
      #pragma unroll
      for (int r = 0; r < 4; r++) {
        float s = fmaxf(acc2[0][r], 0.f) * a3v0 + fmaxf(acc2[1][r], 0.f) * a3v1;
        s += __shfl_xor(s, 1, 64);
        s += __shfl_xor(s, 2, 64);
        s += __shfl_xor(s, 4, 64);
        s += __shfl_xor(s, 8, 64);
        if (ln == 0) sPart[w][mt * 16 + lg * 4 + r] = s;
      }
    }
    __syncthreads();
    if (t < 32) sScore[l0i * 32 + t] = a3s + sPart[0][t] + sPart[1][t] + sPart[2][t] + sPart[3][t];
  }
  __syncthreads();

  // ---- softmax by wave 0 ----------------------------------------------------
  if (w == 0) {
    float s[4], e[4];
    float mx = -3.0e38f;
    #pragma unroll
    for (int i = 0; i < 4; i++) {
      int l = lane + i * 64;
      s[i] = (l < LPAD && sMask[l] > 0.f) ? sScore[l] : -3.0e38f;
      mx = fmaxf(mx, s[i]);
    }
    #pragma unroll
    for (int o = 1; o < 64; o <<= 1) mx = fmaxf(mx, __shfl_xor(mx, o, 64));
    float sum = 0.f;
    #pragma unroll
    for (int i = 0; i < 4; i++) {
      int l = lane + i * 64;
      e[i] = (l < LPAD && sMask[l] > 0.f) ? expf(s[i] - mx) : 0.f;
      sum += e[i];
    }
    #pragma unroll
    for (int o = 1; o < 64; o <<= 1) sum += __shfl_xor(sum, o, 64);
    float invS = 1.f / fmaxf(sum, 1e-30f);
    #pragma unroll
    for (int i = 0; i < 4; i++) {
      int l = lane + i * 64;
      if (l < LPAD) sScore[l] = e[i] * invS;
    }
  }
  __syncthreads();

  // ---- hist_att from L2-hot bf16 table (masked weights are exactly 0) ------
  {
    const int e = t & 63, wg = t >> 6;
    float aw = 0.f;
    for (int l = wg; l < Ln; l += 4)
      aw += sScore[l] * bf2f(emb0b[(size_t)sHid[l] * 64 + e]);
    sRed[wg][e] = aw;
  }
  __syncthreads();
  if (t < 64) {
    float ha = sRed[0][t] + sRed[1][t] + sRed[2][t] + sRed[3][t];
    float tv = sQ[t];
    float* out = base + (size_t)b * FEATn;
    short* outb = baseb + (size_t)b * FEATn;
    float v1 = ha, v2 = tv * ha, v3 = tv - ha;
    out[1344 + t] = v1;  outb[1344 + t] = f2bf(v1);
    out[1536 + t] = v2;  outb[1536 + t] = f2bf(v2);
    out[1600 + t] = v3;  outb[1600 + t] = f2bf(v3);
  }
}

// ---------------- K3: bf16 MFMA GEMM  C = act(A @ W + bias) ------------------
// A: MxK bf16 row-major. Wt: NxK bf16 row-major (pre-transposed weights).
// Computes C^T tiles so the C-store is 4 consecutive n per lane.
__global__ __launch_bounds__(256) void k_gemm_mfma(
    const short* __restrict__ A, const short* __restrict__ Wt,
    const float* __restrict__ bias, void* __restrict__ C,
    int N, int K, int relu, int outbf)
{
  __shared__ short sA[64 * 32] __attribute__((aligned(16)));
  __shared__ short sW[64 * 32] __attribute__((aligned(16)));
  const int t = threadIdx.x;
  const int w = t >> 6, lane = t & 63, ln = lane & 15, lg = lane >> 4;
  const int m0 = blockIdx.x * 64, n0 = blockIdx.y * 64;
  const int wm = (w & 1) * 32, wn = (w >> 1) * 32;

  f4v acc[2][2] = {{(f4v){0,0,0,0},(f4v){0,0,0,0}},{(f4v){0,0,0,0},(f4v){0,0,0,0}}};

  for (int k0 = 0; k0 < K; k0 += 32) {
    #pragma unroll
    for (int i = 0; i < 2; i++) {
      int idx = t + i * 256;
      int r = idx >> 3, c = (idx & 7) << 2;
      s4v av = *(const s4v*)(A + (size_t)(m0 + r) * K + k0 + c);
      *(s4v*)(sA + ((r * 32 + c) ^ ((r & 7) << 2))) = av;
      s4v wv = *(const s4v*)(Wt + (size_t)(n0 + r) * K + k0 + c);
      *(s4v*)(sW + ((r * 32 + c) ^ ((r & 7) << 2))) = wv;
    }
    __syncthreads();

    s8v af[2], wf[2];
    #pragma unroll
    for (int mt = 0; mt < 2; mt++) {
      int row = wm + mt * 16 + ln;
      int idx = row * 32 + lg * 4, swz = (row & 7) << 2;
      s4v h0 = *(const s4v*)(sA + (idx ^ swz));
      s4v h1 = *(const s4v*)(sA + ((idx + 16) ^ swz));
      af[mt] = __builtin_shufflevector(h0, h1, 0,1,2,3,4,5,6,7);
    }
    #pragma unroll
    for (int nt = 0; nt < 2; nt++) {
      int row = wn + nt * 16 + ln;
      int idx = row * 32 + lg * 4, swz = (row & 7) << 2;
      s4v h0 = *(const s4v*)(sW + (idx ^ swz));
      s4v h1 = *(const s4v*)(sW + ((idx + 16) ^ swz));
      wf[nt] = __builtin_shufflevector(h0, h1, 0,1,2,3,4,5,6,7);
    }
    #pragma unroll
    for (int mt = 0; mt < 2; mt++)
      #pragma unroll
      for (int nt = 0; nt < 2; nt++)
        acc[mt][nt] = __builtin_amdgcn_mfma_f32_16x16x32_bf16(wf[nt], af[mt], acc[mt][nt], 0, 0, 0);
    __syncthreads();
  }

  // D[row=n][col=m]: lane(ln,lg): n = wn+nt*16+lg*4+r, m = wm+mt*16+ln
  #pragma unroll
  for (int mt = 0; mt < 2; mt++)
    #pragma unroll
    for (int nt = 0; nt < 2; nt++) {
      int n = n0 + wn + nt * 16 + lg * 4;
      int m = m0 + wm + mt * 16 + ln;
      float4 bz = *(const float4*)(bias + n);
      float4 o;
      o.x = acc[mt][nt][0] + bz.x; o.y = acc[mt][nt][1] + bz.y;
      o.z = acc[mt][nt][2] + bz.z; o.w = acc[mt][nt][3] + bz.w;
      if (relu) {
        o.x = fmaxf(o.x, 0.f); o.y = fmaxf(o.y, 0.f);
        o.z = fmaxf(o.z, 0.f); o.w = fmaxf(o.w, 0.f);
      }
      if (outbf) {
        s4v o4 = { f2bf(o.x), f2bf(o.y), f2bf(o.z), f2bf(o.w) };
        *(s4v*)((short*)C + (size_t)m * N + n) = o4;
      } else {
        *(float4*)((float*)C + (size_t)m * N + n) = o;
      }
    }
}

// ---------------- K4: DCN cross (3 iters) + final head ----------------------
__global__ __launch_bounds__(256) void k_cross_final(
    const float* __restrict__ base, const float* __restrict__ cross_w,
    const float* __restrict__ cross_b, const float* __restrict__ deep3,
    const float* __restrict__ Wh, const float* __restrict__ bh,
    float* __restrict__ out)
{
  __shared__ float shred[4];
  const int b = blockIdx.x, t = threadIdx.x;
  const float* br = base + (size_t)b * FEATn;
  float bs[7], xl[7];
  #pragma unroll
  for (int j = 0; j < 7; j++) {
    int i = t + j * 256;
    float v = (i < FEATn) ? br[i] : 0.f;
    bs[j] = v; xl[j] = v;
  }
  for (int k = 0; k < 3; k++) {
    float p = 0.f;
    #pragma unroll
    for (int j = 0; j < 7; j++) {
      int i = t + j * 256;
      if (i < FEATn) p += xl[j] * cross_w[k * FEATn + i];
    }
    float xw = blk_sum(p, shred);
    #pragma unroll
    for (int j = 0; j < 7; j++) {
      int i = t + j * 256;
      if (i < FEATn) xl[j] = bs[j] * xw + cross_b[k * FEATn + i] + xl[j];
    }
  }
  float p = 0.f;
  #pragma unroll
  for (int j = 0; j < 7; j++) {
    int i = t + j * 256;
    if (i < FEATn) p += xl[j] * Wh[i];
  }
  p += deep3[(size_t)b * 256 + t] * Wh[FEATn + t];
  float tot = blk_sum(p, shred);
  if (t == 0) out[b] = tot + bh[0];
}

// ---------------- launch -----------------------------------------------------
extern "C" void kernel_launch(void* const* d_in, const int* in_sizes, int n_in,
                              void* d_out, int out_size, void* d_ws, size_t ws_size,
                              hipStream_t stream) {
  (void)in_sizes; (void)n_in; (void)out_size; (void)ws_size;
  const int*   user_cat  = (const int*)d_in[0];
  const float* user_num  = (const float*)d_in[1];
  const int*   ctx_cat   = (const int*)d_in[2];
  const float* ctx_num   = (const float*)d_in[3];
  const int*   hist_ids  = (const int*)d_in[4];
  const int*   hist_auth = (const int*)d_in[5];
  const int*   hist_tag  = (const int*)d_in[6];
  const int*   hist_mask = (const int*)d_in[7];
  const int*   item_cat  = (const int*)d_in[8];
  const float* item_num  = (const float*)d_in[9];
  const float* user_emb  = (const float*)d_in[10];
  const float* item_emb  = (const float*)d_in[11];
  const float* ctx_emb   = (const float*)d_in[12];
  const float* Wu = (const float*)d_in[13];  const float* bu = (const float*)d_in[14];
  const float* Wi = (const float*)d_in[15];  const float* bi = (const float*)d_in[16];
  const float* Wc = (const float*)d_in[17];  const float* bc = (const float*)d_in[18];
  const float* A1 = (const float*)d_in[19];  const float* a1 = (const float*)d_in[20];
  const float* A2 = (const float*)d_in[21];  const float* a2 = (const float*)d_in[22];
  const float* A3 = (const float*)d_in[23];  const float* a3 = (const float*)d_in[24];
  const float* cross_w = (const float*)d_in[25];
  const float* cross_b = (const float*)d_in[26];
  const float* D1 = (const float*)d_in[27];  const float* d1 = (const float*)d_in[28];
  const float* D2 = (const float*)d_in[29];  const float* d2 = (const float*)d_in[30];
  const float* D3 = (const float*)d_in[31];  const float* d3 = (const float*)d_in[32];
  const float* Wh = (const float*)d_in[33];  const float* bh = (const float*)d_in[34];

  // workspace (all segment sizes keep 16B alignment)
  float* base  = (float*)d_ws;                          // B x 1664 f32
  float* h3    = base + (size_t)Bn * FEATn;             // B x 256 f32
  float* qterm = h3 + (size_t)Bn * 256;                 // B x 256 f32
  short* baseb = (short*)(qterm + (size_t)Bn * 256);    // B x 1664 bf16
  short* h1b   = baseb + (size_t)Bn * FEATn;            // B x 512 bf16
  short* h2b   = h1b + (size_t)Bn * 512;                // B x 256 bf16
  short* W1f   = h2b + (size_t)Bn * 256;                // 32768
  short* W2f   = W1f + 32768;                           // 32768
  short* A1s   = W2f + 32768;                           // 16384
  short* emb0b = A1s + 16384;                           // 6,400,000
  short* D1t   = emb0b + (size_t)Vn * 64;               // 512 x 1664
  short* D2t   = D1t + (size_t)512 * 1664;              // 256 x 512
  short* D3t   = D2t + (size_t)256 * 512;               // 256 x 256

  k_prep<<<320, 256, 0, stream>>>(A1, A2, W1f, W2f, A1s);
  k_cvt<<<(Vn * En / 4 + 255) / 256, 256, 0, stream>>>(item_emb, emb0b, Vn * En / 4);
  k_trcvt<<<1024, 256, 0, stream>>>(D1, D2, D3, D1t, D2t, D3t);
  k_gather<<<Bn, 256, 0, stream>>>(user_cat, user_num, ctx_cat, ctx_num,
                                   item_cat, item_num, user_emb, item_emb, ctx_emb,
                                   Wu, bu, Wi, bi, Wc, bc,
                                   hist_auth, hist_tag, hist_mask,
                                   A1s, a1, base, baseb, qterm);
  k_attn<<<Bn, 256, 0, stream>>>(hist_ids, hist_mask, emb0b,
                                 W1f, W2f, qterm, a2, A3, a3, base, baseb);
  k_gemm_mfma<<<dim3(Bn / 64, 512 / 64), 256, 0, stream>>>(baseb, D1t, d1, h1b, 512, FEATn, 1, 1);
  k_gemm_mfma<<<dim3(Bn / 64, 256 / 64), 256, 0, stream>>>(h1b, D2t, d2, h2b, 256, 512, 1, 1);
  k_gemm_mfma<<<dim3(Bn / 64, 256 / 64), 256, 0, stream>>>(h2b, D3t, d3, h3, 256, 256, 0, 0);
  k_cross_final<<<Bn, 256, 0, stream>>>(base, cross_w, cross_b, h3, Wh, bh,
                                        (float*)d_out);
}